// Round 4
// baseline (311.830 us; speedup 1.0000x reference)
//
#include <hip/hip_runtime.h>
#include <hip/hip_bf16.h>

typedef __attribute__((ext_vector_type(8))) short short8v;
typedef __attribute__((ext_vector_type(4))) short short4v;
typedef __attribute__((ext_vector_type(4))) float float4v;

__device__ __forceinline__ unsigned short f2bf(float x) {
    unsigned u = __float_as_uint(x);
    unsigned r = (u + 0x7fffu + ((u >> 16) & 1u)) >> 16;
    return (unsigned short)r;
}

__device__ __forceinline__ unsigned lds_off(void* p) {
    return (unsigned)(uintptr_t)(__attribute__((address_space(3))) void*)p;
}

// ---------- branch 1x1 conv + BN + ReLU (a4: CIN=128, a32: CIN=256) ----------
template<int CIN>
__global__ __launch_bounds__(256) void k_branch(
    const float* __restrict__ x, const float* __restrict__ w,
    const float* __restrict__ s, const float* __restrict__ b,
    float* __restrict__ out, int npix) {
    int t = threadIdx.x;
    int f = t & 31;
    int pi = blockIdx.x * 8 + (t >> 5);
    if (pi >= npix) return;
    const float* xr = x + (size_t)pi * CIN;
    float acc = 0.f;
#pragma unroll 4
    for (int c = 0; c < CIN; ++c) acc = fmaf(xr[c], w[c * 32 + f], acc);
    float v = fmaf(acc, s[f], b[f]);
    out[(size_t)pi * 32 + f] = fmaxf(v, 0.f);
}

// ---------- cat builder: a2 (1x1 conv) + bilinear up of a4, a32 -> bf16 ----------
__global__ __launch_bounds__(256) void k_cat(
    const float* __restrict__ feats2, const float* __restrict__ w2,
    const float* __restrict__ s2, const float* __restrict__ b2,
    const float* __restrict__ a4, const float* __restrict__ a32,
    unsigned short* __restrict__ cat) {
    int t = threadIdx.x;
    int f = t & 31;
    int p = blockIdx.x * 8 + (t >> 5);   // 0..65535
    int y = p >> 8, x = p & 255;

    {
        const float* xr = feats2 + (size_t)p * 64;
        float acc = 0.f;
#pragma unroll 4
        for (int c = 0; c < 64; ++c) acc = fmaf(xr[c], w2[c * 32 + f], acc);
        float v = fmaf(acc, s2[f], b2[f]);
        cat[(size_t)p * 96 + f] = f2bf(fmaxf(v, 0.f));
    }
    {
        float sy = fminf(fmaxf(y * 0.5f - 0.25f, 0.f), 127.f);
        float sx = fminf(fmaxf(x * 0.5f - 0.25f, 0.f), 127.f);
        int y0 = (int)sy; float fy = sy - (float)y0; int y1 = min(y0 + 1, 127);
        int x0 = (int)sx; float fx = sx - (float)x0; int x1 = min(x0 + 1, 127);
        float v00 = a4[((size_t)(y0 * 128 + x0)) * 32 + f];
        float v01 = a4[((size_t)(y0 * 128 + x1)) * 32 + f];
        float v10 = a4[((size_t)(y1 * 128 + x0)) * 32 + f];
        float v11 = a4[((size_t)(y1 * 128 + x1)) * 32 + f];
        float vv = (1.f - fy) * ((1.f - fx) * v00 + fx * v01)
                 + fy * ((1.f - fx) * v10 + fx * v11);
        cat[(size_t)p * 96 + 32 + f] = f2bf(vv);
    }
    {
        float sy = fminf(fmaxf((y + 0.5f) * (1.f / 16.f) - 0.5f, 0.f), 15.f);
        float sx = fminf(fmaxf((x + 0.5f) * (1.f / 16.f) - 0.5f, 0.f), 15.f);
        int y0 = (int)sy; float fy = sy - (float)y0; int y1 = min(y0 + 1, 15);
        int x0 = (int)sx; float fx = sx - (float)x0; int x1 = min(x0 + 1, 15);
        float v00 = a32[((size_t)(y0 * 16 + x0)) * 32 + f];
        float v01 = a32[((size_t)(y0 * 16 + x1)) * 32 + f];
        float v10 = a32[((size_t)(y1 * 16 + x0)) * 32 + f];
        float v11 = a32[((size_t)(y1 * 16 + x1)) * 32 + f];
        float vv = (1.f - fy) * ((1.f - fx) * v00 + fx * v01)
                 + fy * ((1.f - fx) * v10 + fx * v11);
        cat[(size_t)p * 96 + 64 + f] = f2bf(vv);
    }
}

// ---------- pack 3x3 fuse weights to MFMA B-fragment order ----------
__global__ __launch_bounds__(256) void k_packf(
    const float* __restrict__ wf, short* __restrict__ wfp) {
    int i = blockIdx.x * 256 + threadIdx.x;   // 0..82943
    if (i >= 82944) return;
    int j = i & 7;
    int l = (i >> 3) & 63;
    int rest = i >> 9;       // 0..161
    int nt = rest % 6;
    int tk = rest / 6;       // 0..26
    int kt = tk % 3, tap = tk / 3;
    int k = kt * 32 + ((l >> 4) << 3) + j;
    int n = nt * 16 + (l & 15);
    wfp[i] = (short)f2bf(wf[((size_t)(tap * 96 + k)) * 96 + n]);
}

// ---------- 3x3 conv via bf16 MFMA implicit GEMM + BN + ReLU -> bf16 ----------
// 1024 blocks, tile 8x8 px; 4 waves in 2x2: wave (wr,wc) -> 32 px rows x 48 ch.
// LDS: 10x10 px halo, 256B/row pitch, chunk-XOR swizzle. 25.6KB -> 6 blocks/CU.
__global__ __launch_bounds__(256, 6) void k_fuse3(
    const unsigned short* __restrict__ catb, const short* __restrict__ wfp,
    const float* __restrict__ sf, const float* __restrict__ bfb,
    unsigned short* __restrict__ featb) {
    __shared__ char Xb[100 * 256];
    int t = threadIdx.x;
    int by = (blockIdx.x >> 5) * 8;
    int bx = (blockIdx.x & 31) * 8;

    if (t < 200) {
        int rp = t >> 1, hf = t & 1;
        int gy = by + rp / 10 - 1;
        int gx = bx + rp % 10 - 1;
        bool ok = (gy >= 0 && gy < 256 && gx >= 0 && gx < 256);
        const unsigned short* src = catb + (size_t)(gy * 256 + gx) * 96 + hf * 48;
        int swz = (rp & 7) << 4;
#pragma unroll
        for (int m = 0; m < 6; ++m) {
            short8v v = {0, 0, 0, 0, 0, 0, 0, 0};
            if (ok) v = *(const short8v*)(src + m * 8);
            *(short8v*)(Xb + rp * 256 + (((hf * 6 + m) * 16) ^ swz)) = v;
        }
    }
    for (int i = t; i < 400; i += 256) {
        int rp = i >> 2, cc = 12 + (i & 3);
        short8v z = {0, 0, 0, 0, 0, 0, 0, 0};
        *(short8v*)(Xb + rp * 256 + ((cc * 16) ^ ((rp & 7) << 4))) = z;
    }
    __syncthreads();

    int lane = t & 63, wid = t >> 6;
    int wr = wid >> 1, wc = wid & 1;
    int l15 = lane & 15, kb = (lane >> 4) * 16;

    float4v acc[2][3];
#pragma unroll
    for (int rb = 0; rb < 2; ++rb)
#pragma unroll
        for (int n = 0; n < 3; ++n)
            acc[rb][n] = (float4v){0.f, 0.f, 0.f, 0.f};

#pragma unroll
    for (int ky = 0; ky < 3; ++ky) {
#pragma unroll
        for (int kx = 0; kx < 3; ++kx) {
#pragma unroll
            for (int kt = 0; kt < 3; ++kt) {
                const short8v* bp = (const short8v*)wfp
                    + (size_t)((((ky * 3 + kx) * 3 + kt) * 6) + wc * 3) * 64 + lane;
                short8v b0 = bp[0], b1 = bp[64], b2 = bp[128];
#pragma unroll
                for (int rb = 0; rb < 2; ++rb) {
                    int R = wr * 32 + rb * 16 + l15;
                    int rp = ((R >> 3) + ky) * 10 + (R & 7) + kx;
                    short8v a = *(short8v*)(Xb + rp * 256
                                 + ((kt * 64 + kb) ^ ((rp & 7) << 4)));
                    acc[rb][0] = __builtin_amdgcn_mfma_f32_16x16x32_bf16(a, b0, acc[rb][0], 0, 0, 0);
                    acc[rb][1] = __builtin_amdgcn_mfma_f32_16x16x32_bf16(a, b1, acc[rb][1], 0, 0, 0);
                    acc[rb][2] = __builtin_amdgcn_mfma_f32_16x16x32_bf16(a, b2, acc[rb][2], 0, 0, 0);
                }
            }
        }
    }

    int g = lane >> 4;
#pragma unroll
    for (int rb = 0; rb < 2; ++rb) {
#pragma unroll
        for (int n = 0; n < 3; ++n) {
            int ch = (wc * 3 + n) * 16 + l15;
            float sc = sf[ch], bi = bfb[ch];
#pragma unroll
            for (int j = 0; j < 4; ++j) {
                int R = wr * 32 + rb * 16 + g * 4 + j;
                int pix = (by + (R >> 3)) * 256 + bx + (R & 7);
                featb[(size_t)pix * 96 + ch] =
                    f2bf(fmaxf(fmaf(acc[rb][n][j], sc, bi), 0.f));
            }
        }
    }
}

// ---------- pack MLP weights into MFMA B-fragment order (bf16) ----------
__global__ __launch_bounds__(256) void k_pack(
    const float* __restrict__ w0, const float* __restrict__ w1,
    short* __restrict__ w0p, short* __restrict__ w1p) {
    int i = blockIdx.x * 256 + threadIdx.x;   // 0..16383
    int j = i & 7;
    int l = (i >> 3) & 63;
    int nt = (i >> 9) & 7;
    int kt = i >> 12;
    int k = kt * 32 + ((l >> 4) << 3) + j;
    int n = nt * 16 + (l & 15);
    w0p[i] = (k < 98) ? (short)f2bf(w0[k * 128 + n]) : (short)0;
    w1p[i] = (short)f2bf(w1[k * 128 + n]);
}

// ---------- fused LIIF query + MLP (bf16 MFMA) + ensemble ----------
// 256 thr = 4 waves; 128 rows = 32 query px. LDS exactly 32KB -> 5 blocks/CU.
// H stored transposed in 4x16 subtiles, read back via ds_read_b64_tr_b16.
__global__ __launch_bounds__(256, 5) void k_mlp3(
    const unsigned short* __restrict__ featb,
    const short* __restrict__ w0p, const float* __restrict__ b0g,
    const short* __restrict__ w1p, const float* __restrict__ b1g,
    const float* __restrict__ w2g, const float* __restrict__ b2g,
    float* __restrict__ out) {
    __shared__ short8v Xs[2048];   // 32768 B exactly
    char* Xb = (char*)Xs;
    int t = threadIdx.x;
    float area_reg;

    // ---- phase 0: gather X = [feat(96) | ry rx | 0-pad] (bf16) ----
    {
        int row = t >> 1, hf = t & 1;
        int pixl = row >> 2, br = row & 3;
        int p = blockIdx.x * 32 + pixl;
        int qy = p >> 9, qx = p & 511;
        float vx = (br & 2) ? 1.f : -1.f;
        float vy = (br & 1) ? 1.f : -1.f;
        float gy = (qy + 0.5f) * (1.f / 256.f) - 1.f;
        float gx = (qx + 0.5f) * (1.f / 256.f) - 1.f;
        float csy = fminf(fmaxf(gy + (vx * (1.f / 256.f) + 1e-6f), -1.f + 1e-6f), 1.f - 1e-6f);
        float csx = fminf(fmaxf(gx + (vy * (1.f / 256.f) + 1e-6f), -1.f + 1e-6f), 1.f - 1e-6f);
        int iy = min(max((int)rintf((csy + 1.f) * 128.f - 0.5f), 0), 255);
        int ix = min(max((int)rintf((csx + 1.f) * 128.f - 0.5f), 0), 255);
        float qcy = (iy + 0.5f) * (1.f / 128.f) - 1.f;
        float qcx = (ix + 0.5f) * (1.f / 128.f) - 1.f;
        float ry = (gy - qcy) * 256.f;
        float rx = (gx - qcx) * 256.f;
        area_reg = fabsf(ry * rx) + 1e-9f;
        const unsigned short* fp = featb + (size_t)(iy * 256 + ix) * 96;
        int rswz = (row & 7) << 4;
        if (hf == 0) {
#pragma unroll
            for (int cc = 0; cc < 8; ++cc) {
                short8v v = *(const short8v*)(fp + cc * 8);
                *(short8v*)(Xb + row * 256 + ((cc * 16) ^ rswz)) = v;
            }
        } else {
#pragma unroll
            for (int cc = 8; cc < 12; ++cc) {
                short8v v = *(const short8v*)(fp + cc * 8);
                *(short8v*)(Xb + row * 256 + ((cc * 16) ^ rswz)) = v;
            }
            short8v vc = {0, 0, 0, 0, 0, 0, 0, 0};
            vc[0] = (short)f2bf(ry); vc[1] = (short)f2bf(rx);
            *(short8v*)(Xb + row * 256 + ((12 * 16) ^ rswz)) = vc;
            short8v z = {0, 0, 0, 0, 0, 0, 0, 0};
#pragma unroll
            for (int cc = 13; cc < 16; ++cc)
                *(short8v*)(Xb + row * 256 + ((cc * 16) ^ rswz)) = z;
        }
    }
    __syncthreads();

    int lane = t & 63, wid = t >> 6;
    int l15 = lane & 15, g = lane >> 4;
    int arow0 = wid * 32 + l15;
    int arow1 = arow0 + 16;
    int kb = g * 16;
    int rs0 = (arow0 & 7) << 4;

    float4v acc[2][8];
#pragma unroll
    for (int rt = 0; rt < 2; ++rt)
#pragma unroll
        for (int nt = 0; nt < 8; ++nt)
            acc[rt][nt] = (float4v){0.f, 0.f, 0.f, 0.f};

    // ---- layer 0: X row-major swizzled, b128 A-reads ----
#pragma unroll
    for (int kt = 0; kt < 4; ++kt) {
        short8v a0 = *(short8v*)(Xb + arow0 * 256 + ((kt * 64 + kb) ^ rs0));
        short8v a1 = *(short8v*)(Xb + arow1 * 256 + ((kt * 64 + kb) ^ rs0));
        const short8v* bp = (const short8v*)w0p + kt * 512 + lane;
#pragma unroll
        for (int nt = 0; nt < 8; ++nt) {
            short8v b = bp[nt * 64];
            acc[0][nt] = __builtin_amdgcn_mfma_f32_16x16x32_bf16(a0, b, acc[0][nt], 0, 0, 0);
            acc[1][nt] = __builtin_amdgcn_mfma_f32_16x16x32_bf16(a1, b, acc[1][nt], 0, 0, 0);
        }
    }
    __syncthreads();   // all X reads done before overwrite

    // ---- H = relu(acc + b0), stored transposed in [kq][rq][4][16] subtiles ----
#pragma unroll
    for (int rt = 0; rt < 2; ++rt) {
        int rq = wid * 2 + rt;
#pragma unroll
        for (int nt = 0; nt < 8; ++nt) {
            float b0v = b0g[nt * 16 + l15];
            short4v hv;
#pragma unroll
            for (int j = 0; j < 4; ++j)
                hv[j] = (short)f2bf(fmaxf(acc[rt][nt][j] + b0v, 0.f));
            int kq = nt * 4 + (l15 >> 2);
            int byteoff = (kq * 8 + rq) * 128 + (l15 & 3) * 32 + g * 8;
            *(short4v*)(Xb + byteoff) = hv;
        }
    }
    __syncthreads();

#pragma unroll
    for (int rt = 0; rt < 2; ++rt)
#pragma unroll
        for (int nt = 0; nt < 8; ++nt)
            acc[rt][nt] = (float4v){0.f, 0.f, 0.f, 0.f};

    // ---- layer 1: A-frags via hardware transpose read ----
    unsigned xb0 = lds_off(Xb) + (unsigned)(l15 * 8);
#pragma unroll
    for (int kt = 0; kt < 4; ++kt) {
        unsigned kqb = (unsigned)(kt * 8 + g * 2);
        unsigned a00 = xb0 + (kqb * 8 + wid * 2) * 128;
        short4v p00, p01, p10, p11;
        asm volatile("ds_read_b64_tr_b16 %0, %1" : "=v"(p00) : "v"(a00));
        asm volatile("ds_read_b64_tr_b16 %0, %1" : "=v"(p01) : "v"(a00 + 1024));
        asm volatile("ds_read_b64_tr_b16 %0, %1" : "=v"(p10) : "v"(a00 + 128));
        asm volatile("ds_read_b64_tr_b16 %0, %1" : "=v"(p11) : "v"(a00 + 1152));
        asm volatile("s_waitcnt lgkmcnt(0)" ::: "memory");
        __builtin_amdgcn_sched_barrier(0);
        short8v a0, a1;
        a0[0] = p00[0]; a0[1] = p00[1]; a0[2] = p00[2]; a0[3] = p00[3];
        a0[4] = p01[0]; a0[5] = p01[1]; a0[6] = p01[2]; a0[7] = p01[3];
        a1[0] = p10[0]; a1[1] = p10[1]; a1[2] = p10[2]; a1[3] = p10[3];
        a1[4] = p11[0]; a1[5] = p11[1]; a1[6] = p11[2]; a1[7] = p11[3];
        const short8v* bp = (const short8v*)w1p + kt * 512 + lane;
#pragma unroll
        for (int nt = 0; nt < 8; ++nt) {
            short8v b = bp[nt * 64];
            acc[0][nt] = __builtin_amdgcn_mfma_f32_16x16x32_bf16(a0, b, acc[0][nt], 0, 0, 0);
            acc[1][nt] = __builtin_amdgcn_mfma_f32_16x16x32_bf16(a1, b, acc[1][nt], 0, 0, 0);
        }
    }

    // ---- fused layer 2 + 16-lane reduce + in-register ensemble ----
    float b1v[8], w2v[8];
#pragma unroll
    for (int nt = 0; nt < 8; ++nt) {
        b1v[nt] = b1g[nt * 16 + l15];
        w2v[nt] = w2g[nt * 16 + l15];
    }
    float part[2][4];
#pragma unroll
    for (int rt = 0; rt < 2; ++rt)
#pragma unroll
        for (int j = 0; j < 4; ++j) part[rt][j] = 0.f;
#pragma unroll
    for (int rt = 0; rt < 2; ++rt)
#pragma unroll
        for (int nt = 0; nt < 8; ++nt)
#pragma unroll
            for (int j = 0; j < 4; ++j)
                part[rt][j] += fmaxf(acc[rt][nt][j] + b1v[nt], 0.f) * w2v[nt];
#pragma unroll
    for (int off = 8; off >= 1; off >>= 1)
#pragma unroll
        for (int rt = 0; rt < 2; ++rt)
#pragma unroll
            for (int j = 0; j < 4; ++j)
                part[rt][j] += __shfl_xor(part[rt][j], off);

    float bb = b2g[0];
#pragma unroll
    for (int rt = 0; rt < 2; ++rt) {
        // area of row 32*wid+16*rt+4*g+j was computed by wave-lane 32*rt+8*g+2*j
        float A0 = __shfl(area_reg, 32 * rt + 8 * g + 0);
        float A1 = __shfl(area_reg, 32 * rt + 8 * g + 2);
        float A2 = __shfl(area_reg, 32 * rt + 8 * g + 4);
        float A3 = __shfl(area_reg, 32 * rt + 8 * g + 6);
        if (l15 == 0) {
            float T = A0 + A1 + A2 + A3;
            float v = (part[rt][0] + bb) * A3 + (part[rt][1] + bb) * A2
                    + (part[rt][2] + bb) * A1 + (part[rt][3] + bb) * A0;
            out[blockIdx.x * 32 + wid * 8 + rt * 4 + g] = v / T;
        }
    }
}

// ---------- host launcher ----------
extern "C" void kernel_launch(void* const* d_in, const int* in_sizes, int n_in,
                              void* d_out, int out_size, void* d_ws, size_t ws_size,
                              hipStream_t stream) {
    const float* feats2 = (const float*)d_in[0];
    const float* feats4 = (const float*)d_in[1];
    const float* feats32 = (const float*)d_in[2];
    const float* w2 = (const float*)d_in[4];
    const float* s2 = (const float*)d_in[5];
    const float* b2 = (const float*)d_in[6];
    const float* w4 = (const float*)d_in[7];
    const float* s4 = (const float*)d_in[8];
    const float* b4 = (const float*)d_in[9];
    const float* w32 = (const float*)d_in[10];
    const float* s32 = (const float*)d_in[11];
    const float* b32 = (const float*)d_in[12];
    const float* wf = (const float*)d_in[13];
    const float* sf = (const float*)d_in[14];
    const float* bf = (const float*)d_in[15];
    const float* mw0 = (const float*)d_in[16];
    const float* mb0 = (const float*)d_in[17];
    const float* mw1 = (const float*)d_in[18];
    const float* mb1 = (const float*)d_in[19];
    const float* mw2 = (const float*)d_in[20];
    const float* mb2 = (const float*)d_in[21];

    float* a4buf = (float*)d_ws;                          // 128*128*32 f32
    float* a32buf = a4buf + 524288;                       // 16*16*32 f32
    unsigned short* catb16 = (unsigned short*)(a32buf + 8192);   // 65536*96 bf16
    unsigned short* featb16 = catb16 + 6291456;                  // 65536*96 bf16
    short* w0p = (short*)(featb16 + 6291456);             // 16384 bf16
    short* w1p = w0p + 16384;
    short* wfp = w1p + 16384;                             // 82944 bf16

    k_pack<<<64, 256, 0, stream>>>(mw0, mw1, w0p, w1p);
    k_packf<<<324, 256, 0, stream>>>(wf, wfp);
    k_branch<128><<<2048, 256, 0, stream>>>(feats4, w4, s4, b4, a4buf, 16384);
    k_branch<256><<<32, 256, 0, stream>>>(feats32, w32, s32, b32, a32buf, 256);
    k_cat<<<8192, 256, 0, stream>>>(feats2, w2, s2, b2, a4buf, a32buf, catb16);
    k_fuse3<<<1024, 256, 0, stream>>>(catb16, wfp, sf, bf, featb16);
    k_mlp3<<<8192, 256, 0, stream>>>(featb16, w0p, mb0, w1p, mb1, mw2, mb2,
                                     (float*)d_out);
}

// Round 5
// 250.305 us; speedup vs baseline: 1.2458x; 1.2458x over previous
//
#include <hip/hip_runtime.h>
#include <hip/hip_bf16.h>

typedef __attribute__((ext_vector_type(8))) short short8v;
typedef __attribute__((ext_vector_type(4))) float float4v;

__device__ __forceinline__ unsigned short f2bf(float x) {
    unsigned u = __float_as_uint(x);
    unsigned r = (u + 0x7fffu + ((u >> 16) & 1u)) >> 16;
    return (unsigned short)r;
}

// ---------- branch 1x1 conv + BN + ReLU (a4: CIN=128, a32: CIN=256) ----------
template<int CIN>
__global__ __launch_bounds__(256) void k_branch(
    const float* __restrict__ x, const float* __restrict__ w,
    const float* __restrict__ s, const float* __restrict__ b,
    float* __restrict__ out, int npix) {
    int t = threadIdx.x;
    int f = t & 31;
    int pi = blockIdx.x * 8 + (t >> 5);
    if (pi >= npix) return;
    const float* xr = x + (size_t)pi * CIN;
    float acc = 0.f;
#pragma unroll 4
    for (int c = 0; c < CIN; ++c) acc = fmaf(xr[c], w[c * 32 + f], acc);
    float v = fmaf(acc, s[f], b[f]);
    out[(size_t)pi * 32 + f] = fmaxf(v, 0.f);
}

// ---------- cat builder: a2 (1x1 conv) + bilinear up of a4, a32 -> bf16 ----------
__global__ __launch_bounds__(256) void k_cat(
    const float* __restrict__ feats2, const float* __restrict__ w2,
    const float* __restrict__ s2, const float* __restrict__ b2,
    const float* __restrict__ a4, const float* __restrict__ a32,
    unsigned short* __restrict__ cat) {
    int t = threadIdx.x;
    int f = t & 31;
    int p = blockIdx.x * 8 + (t >> 5);   // 0..65535
    int y = p >> 8, x = p & 255;

    {
        const float* xr = feats2 + (size_t)p * 64;
        float acc = 0.f;
#pragma unroll 4
        for (int c = 0; c < 64; ++c) acc = fmaf(xr[c], w2[c * 32 + f], acc);
        float v = fmaf(acc, s2[f], b2[f]);
        cat[(size_t)p * 96 + f] = f2bf(fmaxf(v, 0.f));
    }
    {
        float sy = fminf(fmaxf(y * 0.5f - 0.25f, 0.f), 127.f);
        float sx = fminf(fmaxf(x * 0.5f - 0.25f, 0.f), 127.f);
        int y0 = (int)sy; float fy = sy - (float)y0; int y1 = min(y0 + 1, 127);
        int x0 = (int)sx; float fx = sx - (float)x0; int x1 = min(x0 + 1, 127);
        float v00 = a4[((size_t)(y0 * 128 + x0)) * 32 + f];
        float v01 = a4[((size_t)(y0 * 128 + x1)) * 32 + f];
        float v10 = a4[((size_t)(y1 * 128 + x0)) * 32 + f];
        float v11 = a4[((size_t)(y1 * 128 + x1)) * 32 + f];
        float vv = (1.f - fy) * ((1.f - fx) * v00 + fx * v01)
                 + fy * ((1.f - fx) * v10 + fx * v11);
        cat[(size_t)p * 96 + 32 + f] = f2bf(vv);
    }
    {
        float sy = fminf(fmaxf((y + 0.5f) * (1.f / 16.f) - 0.5f, 0.f), 15.f);
        float sx = fminf(fmaxf((x + 0.5f) * (1.f / 16.f) - 0.5f, 0.f), 15.f);
        int y0 = (int)sy; float fy = sy - (float)y0; int y1 = min(y0 + 1, 15);
        int x0 = (int)sx; float fx = sx - (float)x0; int x1 = min(x0 + 1, 15);
        float v00 = a32[((size_t)(y0 * 16 + x0)) * 32 + f];
        float v01 = a32[((size_t)(y0 * 16 + x1)) * 32 + f];
        float v10 = a32[((size_t)(y1 * 16 + x0)) * 32 + f];
        float v11 = a32[((size_t)(y1 * 16 + x1)) * 32 + f];
        float vv = (1.f - fy) * ((1.f - fx) * v00 + fx * v01)
                 + fy * ((1.f - fx) * v10 + fx * v11);
        cat[(size_t)p * 96 + 64 + f] = f2bf(vv);
    }
}

// ---------- pack 3x3 fuse weights to MFMA B-fragment order ----------
__global__ __launch_bounds__(256) void k_packf(
    const float* __restrict__ wf, short* __restrict__ wfp) {
    int i = blockIdx.x * 256 + threadIdx.x;   // 0..82943
    if (i >= 82944) return;
    int j = i & 7;
    int l = (i >> 3) & 63;
    int rest = i >> 9;       // 0..161
    int nt = rest % 6;
    int tk = rest / 6;       // 0..26
    int kt = tk % 3, tap = tk / 3;
    int k = kt * 32 + ((l >> 4) << 3) + j;
    int n = nt * 16 + (l & 15);
    wfp[i] = (short)f2bf(wf[((size_t)(tap * 96 + k)) * 96 + n]);
}

// ---------- 3x3 conv via bf16 MFMA implicit GEMM + BN + ReLU -> bf16 ----------
__global__ __launch_bounds__(256, 6) void k_fuse3(
    const unsigned short* __restrict__ catb, const short* __restrict__ wfp,
    const float* __restrict__ sf, const float* __restrict__ bfb,
    unsigned short* __restrict__ featb) {
    __shared__ char Xb[100 * 256];
    int t = threadIdx.x;
    int by = (blockIdx.x >> 5) * 8;
    int bx = (blockIdx.x & 31) * 8;

    if (t < 200) {
        int rp = t >> 1, hf = t & 1;
        int gy = by + rp / 10 - 1;
        int gx = bx + rp % 10 - 1;
        bool ok = (gy >= 0 && gy < 256 && gx >= 0 && gx < 256);
        const unsigned short* src = catb + (size_t)(gy * 256 + gx) * 96 + hf * 48;
        int swz = (rp & 7) << 4;
#pragma unroll
        for (int m = 0; m < 6; ++m) {
            short8v v = {0, 0, 0, 0, 0, 0, 0, 0};
            if (ok) v = *(const short8v*)(src + m * 8);
            *(short8v*)(Xb + rp * 256 + (((hf * 6 + m) * 16) ^ swz)) = v;
        }
    }
    for (int i = t; i < 400; i += 256) {
        int rp = i >> 2, cc = 12 + (i & 3);
        short8v z = {0, 0, 0, 0, 0, 0, 0, 0};
        *(short8v*)(Xb + rp * 256 + ((cc * 16) ^ ((rp & 7) << 4))) = z;
    }
    __syncthreads();

    int lane = t & 63, wid = t >> 6;
    int wr = wid >> 1, wc = wid & 1;
    int l15 = lane & 15, kb = (lane >> 4) * 16;

    float4v acc[2][3];
#pragma unroll
    for (int rb = 0; rb < 2; ++rb)
#pragma unroll
        for (int n = 0; n < 3; ++n)
            acc[rb][n] = (float4v){0.f, 0.f, 0.f, 0.f};

#pragma unroll
    for (int ky = 0; ky < 3; ++ky) {
#pragma unroll
        for (int kx = 0; kx < 3; ++kx) {
#pragma unroll
            for (int kt = 0; kt < 3; ++kt) {
                const short8v* bp = (const short8v*)wfp
                    + (size_t)((((ky * 3 + kx) * 3 + kt) * 6) + wc * 3) * 64 + lane;
                short8v b0 = bp[0], b1 = bp[64], b2 = bp[128];
#pragma unroll
                for (int rb = 0; rb < 2; ++rb) {
                    int R = wr * 32 + rb * 16 + l15;
                    int rp = ((R >> 3) + ky) * 10 + (R & 7) + kx;
                    short8v a = *(short8v*)(Xb + rp * 256
                                 + ((kt * 64 + kb) ^ ((rp & 7) << 4)));
                    acc[rb][0] = __builtin_amdgcn_mfma_f32_16x16x32_bf16(a, b0, acc[rb][0], 0, 0, 0);
                    acc[rb][1] = __builtin_amdgcn_mfma_f32_16x16x32_bf16(a, b1, acc[rb][1], 0, 0, 0);
                    acc[rb][2] = __builtin_amdgcn_mfma_f32_16x16x32_bf16(a, b2, acc[rb][2], 0, 0, 0);
                }
            }
        }
    }

    int g = lane >> 4;
#pragma unroll
    for (int rb = 0; rb < 2; ++rb) {
#pragma unroll
        for (int n = 0; n < 3; ++n) {
            int ch = (wc * 3 + n) * 16 + l15;
            float sc = sf[ch], bi = bfb[ch];
#pragma unroll
            for (int j = 0; j < 4; ++j) {
                int R = wr * 32 + rb * 16 + g * 4 + j;
                int pix = (by + (R >> 3)) * 256 + bx + (R & 8 - 1 & 7);
                (void)pix;
                int pix2 = (by + (R >> 3)) * 256 + bx + (R & 7);
                featb[(size_t)pix2 * 96 + ch] =
                    f2bf(fmaxf(fmaf(acc[rb][n][j], sc, bi), 0.f));
            }
        }
    }
}

// ---------- pack MLP weights into MFMA B-fragment order (bf16) ----------
__global__ __launch_bounds__(256) void k_pack(
    const float* __restrict__ w0, const float* __restrict__ w1,
    short* __restrict__ w0p, short* __restrict__ w1p) {
    int i = blockIdx.x * 256 + threadIdx.x;   // 0..16383
    int j = i & 7;
    int l = (i >> 3) & 63;
    int nt = (i >> 9) & 7;
    int kt = i >> 12;
    int k = kt * 32 + ((l >> 4) << 3) + j;
    int n = nt * 16 + (l & 15);
    w0p[i] = (k < 98) ? (short)f2bf(w0[k * 128 + n]) : (short)0;
    w1p[i] = (short)f2bf(w1[k * 128 + n]);
}

// ---------- fused LIIF query + MLP (bf16 MFMA, N-split waves) + ensemble ----------
// 4 waves; 128 rows = 32 px. Wave w owns cols [32w,32w+32) for ALL rows ->
// each wave loads only 2/8 of the B-fragments per layer (4x less L2 traffic).
// LDS exactly 32KB -> 5 blocks/CU; no VGPR cap (round-4 spill post-mortem).
__global__ __launch_bounds__(256) void k_mlp4(
    const unsigned short* __restrict__ featb,
    const short* __restrict__ w0p, const float* __restrict__ b0g,
    const short* __restrict__ w1p, const float* __restrict__ b1g,
    const float* __restrict__ w2g, const float* __restrict__ b2g,
    float* __restrict__ out) {
    __shared__ short8v Xs[2048];   // 32768 B exactly
    char* Xb = (char*)Xs;
    int t = threadIdx.x;
    float area_reg;

    // ---- phase 0: gather X = [feat(96) | ry rx | 0-pad] (bf16) ----
    {
        int row = t >> 1, hf = t & 1;
        int pixl = row >> 2, br = row & 3;
        int p = blockIdx.x * 32 + pixl;
        int qy = p >> 9, qx = p & 511;
        float vx = (br & 2) ? 1.f : -1.f;
        float vy = (br & 1) ? 1.f : -1.f;
        float gy = (qy + 0.5f) * (1.f / 256.f) - 1.f;
        float gx = (qx + 0.5f) * (1.f / 256.f) - 1.f;
        float csy = fminf(fmaxf(gy + (vx * (1.f / 256.f) + 1e-6f), -1.f + 1e-6f), 1.f - 1e-6f);
        float csx = fminf(fmaxf(gx + (vy * (1.f / 256.f) + 1e-6f), -1.f + 1e-6f), 1.f - 1e-6f);
        int iy = min(max((int)rintf((csy + 1.f) * 128.f - 0.5f), 0), 255);
        int ix = min(max((int)rintf((csx + 1.f) * 128.f - 0.5f), 0), 255);
        float qcy = (iy + 0.5f) * (1.f / 128.f) - 1.f;
        float qcx = (ix + 0.5f) * (1.f / 128.f) - 1.f;
        float ry = (gy - qcy) * 256.f;
        float rx = (gx - qcx) * 256.f;
        area_reg = fabsf(ry * rx) + 1e-9f;
        const unsigned short* fp = featb + (size_t)(iy * 256 + ix) * 96;
        int rswz = (row & 7) << 4;
        if (hf == 0) {
#pragma unroll
            for (int cc = 0; cc < 8; ++cc) {
                short8v v = *(const short8v*)(fp + cc * 8);
                *(short8v*)(Xb + row * 256 + ((cc * 16) ^ rswz)) = v;
            }
        } else {
#pragma unroll
            for (int cc = 8; cc < 12; ++cc) {
                short8v v = *(const short8v*)(fp + cc * 8);
                *(short8v*)(Xb + row * 256 + ((cc * 16) ^ rswz)) = v;
            }
            short8v vc = {0, 0, 0, 0, 0, 0, 0, 0};
            vc[0] = (short)f2bf(ry); vc[1] = (short)f2bf(rx);
            *(short8v*)(Xb + row * 256 + ((12 * 16) ^ rswz)) = vc;
            short8v z = {0, 0, 0, 0, 0, 0, 0, 0};
#pragma unroll
            for (int cc = 13; cc < 16; ++cc)
                *(short8v*)(Xb + row * 256 + ((cc * 16) ^ rswz)) = z;
        }
    }
    __syncthreads();

    int lane = t & 63, wid = t >> 6;
    int l15 = lane & 15, g = lane >> 4;
    int rs = (l15 & 7) << 4;            // arow&7 == l15&7 for arow = r*16+l15
    int kb = g * 16;

    float4v acc[8][2];
#pragma unroll
    for (int r = 0; r < 8; ++r)
#pragma unroll
        for (int n = 0; n < 2; ++n)
            acc[r][n] = (float4v){0.f, 0.f, 0.f, 0.f};

    // ---- layer 0: rows 0..128 x this wave's 32 cols ----
#pragma unroll
    for (int kt = 0; kt < 4; ++kt) {
        const short8v* bp = (const short8v*)w0p + (kt * 8 + wid * 2) * 64 + lane;
        short8v b0 = bp[0], b1 = bp[64];
#pragma unroll
        for (int r = 0; r < 8; ++r) {
            short8v a = *(short8v*)(Xb + (r * 16 + l15) * 256 + ((kt * 64 + kb) ^ rs));
            acc[r][0] = __builtin_amdgcn_mfma_f32_16x16x32_bf16(a, b0, acc[r][0], 0, 0, 0);
            acc[r][1] = __builtin_amdgcn_mfma_f32_16x16x32_bf16(a, b1, acc[r][1], 0, 0, 0);
        }
    }
    __syncthreads();   // all X reads done before overwrite

    // ---- H = relu(acc + b0) -> same LDS, row-major swizzled ----
#pragma unroll
    for (int n = 0; n < 2; ++n) {
        int colg = (wid * 2 + n) * 16 + l15;
        float b0v = b0g[colg];
#pragma unroll
        for (int r = 0; r < 8; ++r) {
#pragma unroll
            for (int j = 0; j < 4; ++j) {
                int rr = r * 16 + g * 4 + j;
                *(short*)(Xb + rr * 256 + ((colg * 2) ^ ((rr & 7) << 4))) =
                    (short)f2bf(fmaxf(acc[r][n][j] + b0v, 0.f));
            }
        }
    }
    __syncthreads();

#pragma unroll
    for (int r = 0; r < 8; ++r)
#pragma unroll
        for (int n = 0; n < 2; ++n)
            acc[r][n] = (float4v){0.f, 0.f, 0.f, 0.f};

    // ---- layer 1 ----
#pragma unroll
    for (int kt = 0; kt < 4; ++kt) {
        const short8v* bp = (const short8v*)w1p + (kt * 8 + wid * 2) * 64 + lane;
        short8v b0 = bp[0], b1 = bp[64];
#pragma unroll
        for (int r = 0; r < 8; ++r) {
            short8v a = *(short8v*)(Xb + (r * 16 + l15) * 256 + ((kt * 64 + kb) ^ rs));
            acc[r][0] = __builtin_amdgcn_mfma_f32_16x16x32_bf16(a, b0, acc[r][0], 0, 0, 0);
            acc[r][1] = __builtin_amdgcn_mfma_f32_16x16x32_bf16(a, b1, acc[r][1], 0, 0, 0);
        }
    }

    // ---- fused layer 2 (this wave's 32-col slice) + 16-lane reduce ----
    float b1v[2], w2v[2];
#pragma unroll
    for (int n = 0; n < 2; ++n) {
        int colg = (wid * 2 + n) * 16 + l15;
        b1v[n] = b1g[colg];
        w2v[n] = w2g[colg];
    }
    float part[8][4];
#pragma unroll
    for (int r = 0; r < 8; ++r)
#pragma unroll
        for (int j = 0; j < 4; ++j) {
            float s = fmaxf(acc[r][0][j] + b1v[0], 0.f) * w2v[0]
                    + fmaxf(acc[r][1][j] + b1v[1], 0.f) * w2v[1];
            part[r][j] = s;
        }
#pragma unroll
    for (int off = 8; off >= 1; off >>= 1)
#pragma unroll
        for (int r = 0; r < 8; ++r)
#pragma unroll
            for (int j = 0; j < 4; ++j)
                part[r][j] += __shfl_xor(part[r][j], off);

    __syncthreads();   // all H reads done; X region reusable as f32 scratch
    float* Xf = (float*)Xb;
    if (l15 == 0) {
#pragma unroll
        for (int r = 0; r < 8; ++r)
#pragma unroll
            for (int j = 0; j < 4; ++j)
                Xf[wid * 128 + r * 16 + g * 4 + j] = part[r][j];
    }
    if ((t & 1) == 0) Xf[512 + (t >> 1)] = area_reg;
    __syncthreads();

    // ---- cross-wave sum + local ensemble (swapped diagonal areas) ----
    if (t < 32) {
        float bb = b2g[0];
        float pr[4], ar[4];
#pragma unroll
        for (int br = 0; br < 4; ++br) {
            int row = t * 4 + br;
            pr[br] = Xf[row] + Xf[128 + row] + Xf[256 + row] + Xf[384 + row] + bb;
            ar[br] = Xf[512 + row];
        }
        out[blockIdx.x * 32 + t] =
            (pr[0] * ar[3] + pr[1] * ar[2] + pr[2] * ar[1] + pr[3] * ar[0])
            / (ar[0] + ar[1] + ar[2] + ar[3]);
    }
}

// ---------- host launcher ----------
extern "C" void kernel_launch(void* const* d_in, const int* in_sizes, int n_in,
                              void* d_out, int out_size, void* d_ws, size_t ws_size,
                              hipStream_t stream) {
    const float* feats2 = (const float*)d_in[0];
    const float* feats4 = (const float*)d_in[1];
    const float* feats32 = (const float*)d_in[2];
    const float* w2 = (const float*)d_in[4];
    const float* s2 = (const float*)d_in[5];
    const float* b2 = (const float*)d_in[6];
    const float* w4 = (const float*)d_in[7];
    const float* s4 = (const float*)d_in[8];
    const float* b4 = (const float*)d_in[9];
    const float* w32 = (const float*)d_in[10];
    const float* s32 = (const float*)d_in[11];
    const float* b32 = (const float*)d_in[12];
    const float* wf = (const float*)d_in[13];
    const float* sf = (const float*)d_in[14];
    const float* bf = (const float*)d_in[15];
    const float* mw0 = (const float*)d_in[16];
    const float* mb0 = (const float*)d_in[17];
    const float* mw1 = (const float*)d_in[18];
    const float* mb1 = (const float*)d_in[19];
    const float* mw2 = (const float*)d_in[20];
    const float* mb2 = (const float*)d_in[21];

    float* a4buf = (float*)d_ws;                          // 128*128*32 f32
    float* a32buf = a4buf + 524288;                       // 16*16*32 f32
    unsigned short* catb16 = (unsigned short*)(a32buf + 8192);   // 65536*96 bf16
    unsigned short* featb16 = catb16 + 6291456;                  // 65536*96 bf16
    short* w0p = (short*)(featb16 + 6291456);             // 16384 bf16
    short* w1p = w0p + 16384;
    short* wfp = w1p + 16384;                             // 82944 bf16

    k_pack<<<64, 256, 0, stream>>>(mw0, mw1, w0p, w1p);
    k_packf<<<324, 256, 0, stream>>>(wf, wfp);
    k_branch<128><<<2048, 256, 0, stream>>>(feats4, w4, s4, b4, a4buf, 16384);
    k_branch<256><<<32, 256, 0, stream>>>(feats32, w32, s32, b32, a32buf, 256);
    k_cat<<<8192, 256, 0, stream>>>(feats2, w2, s2, b2, a4buf, a32buf, catb16);
    k_fuse3<<<1024, 256, 0, stream>>>(catb16, wfp, sf, bf, featb16);
    k_mlp4<<<8192, 256, 0, stream>>>(featb16, w0p, mb0, w1p, mb1, mw2, mb2,
                                     (float*)d_out);
}

// Round 6
// 188.430 us; speedup vs baseline: 1.6549x; 1.3284x over previous
//
#include <hip/hip_runtime.h>
#include <hip/hip_bf16.h>

typedef __attribute__((ext_vector_type(8))) short short8v;
typedef __attribute__((ext_vector_type(4))) float float4v;

__device__ __forceinline__ unsigned short f2bf(float x) {
    unsigned u = __float_as_uint(x);
    unsigned r = (u + 0x7fffu + ((u >> 16) & 1u)) >> 16;
    return (unsigned short)r;
}
__device__ __forceinline__ float bf2f(unsigned short u) {
    return __uint_as_float((unsigned)u << 16);
}

// ---------- branch 1x1 conv + BN + ReLU (a4: CIN=128, a32: CIN=256) ----------
template<int CIN>
__global__ __launch_bounds__(256) void k_branch(
    const float* __restrict__ x, const float* __restrict__ w,
    const float* __restrict__ s, const float* __restrict__ b,
    float* __restrict__ out, int npix) {
    int t = threadIdx.x;
    int f = t & 31;
    int pi = blockIdx.x * 8 + (t >> 5);
    if (pi >= npix) return;
    const float* xr = x + (size_t)pi * CIN;
    float acc = 0.f;
#pragma unroll 4
    for (int c = 0; c < CIN; ++c) acc = fmaf(xr[c], w[c * 32 + f], acc);
    float v = fmaf(acc, s[f], b[f]);
    out[(size_t)pi * 32 + f] = fmaxf(v, 0.f);
}

// ---------- cat builder: a2 (1x1 conv) + bilinear up of a4, a32 -> bf16 ----------
__global__ __launch_bounds__(256) void k_cat(
    const float* __restrict__ feats2, const float* __restrict__ w2,
    const float* __restrict__ s2, const float* __restrict__ b2,
    const float* __restrict__ a4, const float* __restrict__ a32,
    unsigned short* __restrict__ cat) {
    int t = threadIdx.x;
    int f = t & 31;
    int p = blockIdx.x * 8 + (t >> 5);   // 0..65535
    int y = p >> 8, x = p & 255;

    {
        const float* xr = feats2 + (size_t)p * 64;
        float acc = 0.f;
#pragma unroll 4
        for (int c = 0; c < 64; ++c) acc = fmaf(xr[c], w2[c * 32 + f], acc);
        float v = fmaf(acc, s2[f], b2[f]);
        cat[(size_t)p * 96 + f] = f2bf(fmaxf(v, 0.f));
    }
    {
        float sy = fminf(fmaxf(y * 0.5f - 0.25f, 0.f), 127.f);
        float sx = fminf(fmaxf(x * 0.5f - 0.25f, 0.f), 127.f);
        int y0 = (int)sy; float fy = sy - (float)y0; int y1 = min(y0 + 1, 127);
        int x0 = (int)sx; float fx = sx - (float)x0; int x1 = min(x0 + 1, 127);
        float v00 = a4[((size_t)(y0 * 128 + x0)) * 32 + f];
        float v01 = a4[((size_t)(y0 * 128 + x1)) * 32 + f];
        float v10 = a4[((size_t)(y1 * 128 + x0)) * 32 + f];
        float v11 = a4[((size_t)(y1 * 128 + x1)) * 32 + f];
        float vv = (1.f - fy) * ((1.f - fx) * v00 + fx * v01)
                 + fy * ((1.f - fx) * v10 + fx * v11);
        cat[(size_t)p * 96 + 32 + f] = f2bf(vv);
    }
    {
        float sy = fminf(fmaxf((y + 0.5f) * (1.f / 16.f) - 0.5f, 0.f), 15.f);
        float sx = fminf(fmaxf((x + 0.5f) * (1.f / 16.f) - 0.5f, 0.f), 15.f);
        int y0 = (int)sy; float fy = sy - (float)y0; int y1 = min(y0 + 1, 15);
        int x0 = (int)sx; float fx = sx - (float)x0; int x1 = min(x0 + 1, 15);
        float v00 = a32[((size_t)(y0 * 16 + x0)) * 32 + f];
        float v01 = a32[((size_t)(y0 * 16 + x1)) * 32 + f];
        float v10 = a32[((size_t)(y1 * 16 + x0)) * 32 + f];
        float v11 = a32[((size_t)(y1 * 16 + x1)) * 32 + f];
        float vv = (1.f - fy) * ((1.f - fx) * v00 + fx * v01)
                 + fy * ((1.f - fx) * v10 + fx * v11);
        cat[(size_t)p * 96 + 64 + f] = f2bf(vv);
    }
}

// ---------- pack 3x3 fuse weights to MFMA B-fragment order ----------
__global__ __launch_bounds__(256) void k_packf(
    const float* __restrict__ wf, short* __restrict__ wfp) {
    int i = blockIdx.x * 256 + threadIdx.x;   // 0..82943
    if (i >= 82944) return;
    int j = i & 7;
    int l = (i >> 3) & 63;
    int rest = i >> 9;       // 0..161
    int nt = rest % 6;
    int tk = rest / 6;       // 0..26
    int kt = tk % 3, tap = tk / 3;
    int k = kt * 32 + ((l >> 4) << 3) + j;
    int n = nt * 16 + (l & 15);
    wfp[i] = (short)f2bf(wf[((size_t)(tap * 96 + k)) * 96 + n]);
}

// ---------- pack W1 (4 kt) and W0-feat (3 kt) into B-frag order ----------
__global__ __launch_bounds__(256) void k_pack2(
    const float* __restrict__ w0, const float* __restrict__ w1,
    short* __restrict__ w1p, short* __restrict__ w0fp) {
    int i = blockIdx.x * 256 + threadIdx.x;   // 0..28671
    if (i < 16384) {
        int j = i & 7;
        int l = (i >> 3) & 63;
        int nt = (i >> 9) & 7;
        int kt = i >> 12;
        int k = kt * 32 + ((l >> 4) << 3) + j;
        int n = nt * 16 + (l & 15);
        w1p[i] = (short)f2bf(w1[k * 128 + n]);
    } else {
        int i2 = i - 16384;                   // 0..12287
        int j = i2 & 7;
        int l = (i2 >> 3) & 63;
        int nt = (i2 >> 9) & 7;
        int kt = i2 >> 12;                    // 0..2
        int k = kt * 32 + ((l >> 4) << 3) + j;   // 0..95
        int n = nt * 16 + (l & 15);
        w0fp[i2] = (short)f2bf(w0[k * 128 + n]);
    }
}

// ---------- 3x3 conv (MFMA) + BN + ReLU -> feat (LDS) -> G = feat @ W0f ----------
// 1024 blocks, tile 8x8 px. Conv: waves 2x2 (rows x ch). G-stage: waves N-split.
__global__ __launch_bounds__(256, 4) void k_fuseG(
    const unsigned short* __restrict__ catb, const short* __restrict__ wfp,
    const float* __restrict__ sf, const float* __restrict__ bfb,
    const short* __restrict__ w0fp, unsigned short* __restrict__ G) {
    __shared__ char Xb[100 * 256];
    int t = threadIdx.x;
    int by = (blockIdx.x >> 5) * 8;
    int bx = (blockIdx.x & 31) * 8;

    if (t < 200) {
        int rp = t >> 1, hf = t & 1;
        int gy = by + rp / 10 - 1;
        int gx = bx + rp % 10 - 1;
        bool ok = (gy >= 0 && gy < 256 && gx >= 0 && gx < 256);
        const unsigned short* src = catb + (size_t)(gy * 256 + gx) * 96 + hf * 48;
        int swz = (rp & 7) << 4;
#pragma unroll
        for (int m = 0; m < 6; ++m) {
            short8v v = {0, 0, 0, 0, 0, 0, 0, 0};
            if (ok) v = *(const short8v*)(src + m * 8);
            *(short8v*)(Xb + rp * 256 + (((hf * 6 + m) * 16) ^ swz)) = v;
        }
    }
    __syncthreads();

    int lane = t & 63, wid = t >> 6;
    int wr = wid >> 1, wc = wid & 1;
    int l15 = lane & 15, g = lane >> 4, kb = g * 16;

    float4v acc[2][3];
#pragma unroll
    for (int rb = 0; rb < 2; ++rb)
#pragma unroll
        for (int n = 0; n < 3; ++n)
            acc[rb][n] = (float4v){0.f, 0.f, 0.f, 0.f};

#pragma unroll
    for (int ky = 0; ky < 3; ++ky) {
#pragma unroll
        for (int kx = 0; kx < 3; ++kx) {
#pragma unroll
            for (int kt = 0; kt < 3; ++kt) {
                const short8v* bp = (const short8v*)wfp
                    + (size_t)((((ky * 3 + kx) * 3 + kt) * 6) + wc * 3) * 64 + lane;
                short8v b0 = bp[0], b1 = bp[64], b2 = bp[128];
#pragma unroll
                for (int rb = 0; rb < 2; ++rb) {
                    int R = wr * 32 + rb * 16 + l15;
                    int rp = ((R >> 3) + ky) * 10 + (R & 7) + kx;
                    short8v a = *(short8v*)(Xb + rp * 256
                                 + ((kt * 64 + kb) ^ ((rp & 7) << 4)));
                    acc[rb][0] = __builtin_amdgcn_mfma_f32_16x16x32_bf16(a, b0, acc[rb][0], 0, 0, 0);
                    acc[rb][1] = __builtin_amdgcn_mfma_f32_16x16x32_bf16(a, b1, acc[rb][1], 0, 0, 0);
                    acc[rb][2] = __builtin_amdgcn_mfma_f32_16x16x32_bf16(a, b2, acc[rb][2], 0, 0, 0);
                }
            }
        }
    }
    __syncthreads();   // conv LDS reads done; Xb reusable

    // feat (bf16, BN+ReLU applied) -> Xb as [64 rows][96 ch], pitch 256, swizzled
#pragma unroll
    for (int rb = 0; rb < 2; ++rb) {
#pragma unroll
        for (int n = 0; n < 3; ++n) {
            int ch = (wc * 3 + n) * 16 + l15;
            float sc = sf[ch], bi = bfb[ch];
#pragma unroll
            for (int j = 0; j < 4; ++j) {
                int R = wr * 32 + rb * 16 + g * 4 + j;
                *(short*)(Xb + R * 256 + ((ch * 2) ^ ((R & 7) << 4))) =
                    (short)f2bf(fmaxf(fmaf(acc[rb][n][j], sc, bi), 0.f));
            }
        }
    }
    __syncthreads();

    // G-stage: 64 rows x 128 cols, K=96. Wave wid owns cols [32*wid, 32*wid+32).
    float4v a2[4][2];
#pragma unroll
    for (int r = 0; r < 4; ++r)
#pragma unroll
        for (int n = 0; n < 2; ++n)
            a2[r][n] = (float4v){0.f, 0.f, 0.f, 0.f};

#pragma unroll
    for (int kt = 0; kt < 3; ++kt) {
        const short8v* bp = (const short8v*)w0fp + (kt * 8 + wid * 2) * 64 + lane;
        short8v b0 = bp[0], b1 = bp[64];
#pragma unroll
        for (int r = 0; r < 4; ++r) {
            int row = r * 16 + l15;
            short8v a = *(short8v*)(Xb + row * 256 + ((kt * 64 + kb) ^ ((row & 7) << 4)));
            a2[r][0] = __builtin_amdgcn_mfma_f32_16x16x32_bf16(a, b0, a2[r][0], 0, 0, 0);
            a2[r][1] = __builtin_amdgcn_mfma_f32_16x16x32_bf16(a, b1, a2[r][1], 0, 0, 0);
        }
    }

#pragma unroll
    for (int r = 0; r < 4; ++r) {
#pragma unroll
        for (int n = 0; n < 2; ++n) {
            int colg = (wid * 2 + n) * 16 + l15;
#pragma unroll
            for (int j = 0; j < 4; ++j) {
                int R = r * 16 + g * 4 + j;
                int pix = (by + (R >> 3)) * 256 + bx + (R & 7);
                G[(size_t)pix * 128 + colg] = f2bf(a2[r][n][j]);
            }
        }
    }
}

// ---------- fused LIIF query: gather G + rank-2 correct + relu -> layer1 MFMA ----------
// 8192 blocks (XCD-swizzled), 4 waves, 32 px = 128 rows. LDS exactly 32KB.
__global__ __launch_bounds__(256) void k_mlp5(
    const unsigned short* __restrict__ G,
    const float* __restrict__ w0g, const float* __restrict__ b0g,
    const short* __restrict__ w1p, const float* __restrict__ b1g,
    const float* __restrict__ w2g, const float* __restrict__ b2g,
    float* __restrict__ out) {
    __shared__ short8v Xs[2048];   // 32768 B exactly
    char* Xb = (char*)Xs;
    int t = threadIdx.x;
    int swzb = ((blockIdx.x & 7) << 10) + (blockIdx.x >> 3);   // bijective XCD swizzle
    int pixbase = swzb * 32;

    // ---- phase A: H = relu(G[cell] + ry*W0y + rx*W0x + b0), vectorized ----
    {
        int ds = t & 7, rowg = t >> 3;
        int d0 = ds * 16;
        float wy[16], wx[16], bb0[16];
#pragma unroll
        for (int d = 0; d < 16; ++d) {
            wy[d] = w0g[96 * 128 + d0 + d];
            wx[d] = w0g[97 * 128 + d0 + d];
            bb0[d] = b0g[d0 + d];
        }
#pragma unroll
        for (int k = 0; k < 4; ++k) {
            int row = rowg + 32 * k;
            int pixl = row >> 2, br = row & 3;
            int p = pixbase + pixl;
            int qy = p >> 9, qx = p & 511;
            float vx = (br & 2) ? 1.f : -1.f;
            float vy = (br & 1) ? 1.f : -1.f;
            float gy = (qy + 0.5f) * (1.f / 256.f) - 1.f;
            float gx = (qx + 0.5f) * (1.f / 256.f) - 1.f;
            float csy = fminf(fmaxf(gy + (vx * (1.f / 256.f) + 1e-6f), -1.f + 1e-6f), 1.f - 1e-6f);
            float csx = fminf(fmaxf(gx + (vy * (1.f / 256.f) + 1e-6f), -1.f + 1e-6f), 1.f - 1e-6f);
            int iy = min(max((int)rintf((csy + 1.f) * 128.f - 0.5f), 0), 255);
            int ix = min(max((int)rintf((csx + 1.f) * 128.f - 0.5f), 0), 255);
            float ry = (gy - ((iy + 0.5f) * (1.f / 128.f) - 1.f)) * 256.f;
            float rx = (gx - ((ix + 0.5f) * (1.f / 128.f) - 1.f)) * 256.f;
            const unsigned short* gp = G + ((size_t)(iy * 256 + ix)) * 128 + d0;
            short8v g0 = *(const short8v*)gp;
            short8v g1 = *(const short8v*)(gp + 8);
            short8v h0, h1;
#pragma unroll
            for (int d = 0; d < 8; ++d) {
                float v0 = bf2f((unsigned short)g0[d])
                         + fmaf(ry, wy[d], fmaf(rx, wx[d], bb0[d]));
                h0[d] = (short)f2bf(fmaxf(v0, 0.f));
                float v1 = bf2f((unsigned short)g1[d])
                         + fmaf(ry, wy[8 + d], fmaf(rx, wx[8 + d], bb0[8 + d]));
                h1[d] = (short)f2bf(fmaxf(v1, 0.f));
            }
            int sw = (row & 7) << 4;
            *(short8v*)(Xb + row * 256 + ((d0 * 2) ^ sw)) = h0;
            *(short8v*)(Xb + row * 256 + ((d0 * 2 + 16) ^ sw)) = h1;
        }
    }
    __syncthreads();

    int lane = t & 63, wid = t >> 6;
    int l15 = lane & 15, g = lane >> 4;
    int rs = (l15 & 7) << 4;
    int kb = g * 16;

    float4v acc[8][2];
#pragma unroll
    for (int r = 0; r < 8; ++r)
#pragma unroll
        for (int n = 0; n < 2; ++n)
            acc[r][n] = (float4v){0.f, 0.f, 0.f, 0.f};

    // ---- layer 1: 128 rows x wave's 32 cols ----
#pragma unroll
    for (int kt = 0; kt < 4; ++kt) {
        const short8v* bp = (const short8v*)w1p + (kt * 8 + wid * 2) * 64 + lane;
        short8v b0 = bp[0], b1 = bp[64];
#pragma unroll
        for (int r = 0; r < 8; ++r) {
            short8v a = *(short8v*)(Xb + (r * 16 + l15) * 256 + ((kt * 64 + kb) ^ rs));
            acc[r][0] = __builtin_amdgcn_mfma_f32_16x16x32_bf16(a, b0, acc[r][0], 0, 0, 0);
            acc[r][1] = __builtin_amdgcn_mfma_f32_16x16x32_bf16(a, b1, acc[r][1], 0, 0, 0);
        }
    }

    // ---- fused layer 2 (wave's 32-col slice) + 16-lane reduce ----
    float b1v[2], w2v[2];
#pragma unroll
    for (int n = 0; n < 2; ++n) {
        int colg = (wid * 2 + n) * 16 + l15;
        b1v[n] = b1g[colg];
        w2v[n] = w2g[colg];
    }
    float part[8][4];
#pragma unroll
    for (int r = 0; r < 8; ++r)
#pragma unroll
        for (int j = 0; j < 4; ++j)
            part[r][j] = fmaxf(acc[r][0][j] + b1v[0], 0.f) * w2v[0]
                       + fmaxf(acc[r][1][j] + b1v[1], 0.f) * w2v[1];
#pragma unroll
    for (int off = 8; off >= 1; off >>= 1)
#pragma unroll
        for (int r = 0; r < 8; ++r)
#pragma unroll
            for (int j = 0; j < 4; ++j)
                part[r][j] += __shfl_xor(part[r][j], off);

    __syncthreads();   // all H reads done; reuse Xb as f32 scratch
    float* Xf = (float*)Xb;
    if (l15 == 0) {
#pragma unroll
        for (int r = 0; r < 8; ++r)
#pragma unroll
            for (int j = 0; j < 4; ++j)
                Xf[wid * 128 + r * 16 + g * 4 + j] = part[r][j];
    }
    __syncthreads();

    // ---- cross-wave sum + area recompute + local ensemble ----
    if (t < 32) {
        float bb = b2g[0];
        int p = pixbase + t;
        int qy = p >> 9, qx = p & 511;
        float gy = (qy + 0.5f) * (1.f / 256.f) - 1.f;
        float gx = (qx + 0.5f) * (1.f / 256.f) - 1.f;
        float pr[4], ar[4];
#pragma unroll
        for (int br = 0; br < 4; ++br) {
            float vx = (br & 2) ? 1.f : -1.f;
            float vy = (br & 1) ? 1.f : -1.f;
            float csy = fminf(fmaxf(gy + (vx * (1.f / 256.f) + 1e-6f), -1.f + 1e-6f), 1.f - 1e-6f);
            float csx = fminf(fmaxf(gx + (vy * (1.f / 256.f) + 1e-6f), -1.f + 1e-6f), 1.f - 1e-6f);
            int iy = min(max((int)rintf((csy + 1.f) * 128.f - 0.5f), 0), 255);
            int ix = min(max((int)rintf((csx + 1.f) * 128.f - 0.5f), 0), 255);
            float ry = (gy - ((iy + 0.5f) * (1.f / 128.f) - 1.f)) * 256.f;
            float rx = (gx - ((ix + 0.5f) * (1.f / 128.f) - 1.f)) * 256.f;
            ar[br] = fabsf(ry * rx) + 1e-9f;
            int row = t * 4 + br;
            pr[br] = Xf[row] + Xf[128 + row] + Xf[256 + row] + Xf[384 + row] + bb;
        }
        out[pixbase + t] =
            (pr[0] * ar[3] + pr[1] * ar[2] + pr[2] * ar[1] + pr[3] * ar[0])
            / (ar[0] + ar[1] + ar[2] + ar[3]);
    }
}

// ---------- host launcher ----------
extern "C" void kernel_launch(void* const* d_in, const int* in_sizes, int n_in,
                              void* d_out, int out_size, void* d_ws, size_t ws_size,
                              hipStream_t stream) {
    const float* feats2 = (const float*)d_in[0];
    const float* feats4 = (const float*)d_in[1];
    const float* feats32 = (const float*)d_in[2];
    const float* w2 = (const float*)d_in[4];
    const float* s2 = (const float*)d_in[5];
    const float* b2 = (const float*)d_in[6];
    const float* w4 = (const float*)d_in[7];
    const float* s4 = (const float*)d_in[8];
    const float* b4 = (const float*)d_in[9];
    const float* w32 = (const float*)d_in[10];
    const float* s32 = (const float*)d_in[11];
    const float* b32 = (const float*)d_in[12];
    const float* wf = (const float*)d_in[13];
    const float* sf = (const float*)d_in[14];
    const float* bf = (const float*)d_in[15];
    const float* mw0 = (const float*)d_in[16];
    const float* mb0 = (const float*)d_in[17];
    const float* mw1 = (const float*)d_in[18];
    const float* mb1 = (const float*)d_in[19];
    const float* mw2 = (const float*)d_in[20];
    const float* mb2 = (const float*)d_in[21];

    float* a4buf = (float*)d_ws;                          // 128*128*32 f32
    float* a32buf = a4buf + 524288;                       // 16*16*32 f32
    unsigned short* catb16 = (unsigned short*)(a32buf + 8192);   // 65536*96 bf16
    unsigned short* Gbuf = catb16 + 6291456;                     // 65536*128 bf16
    short* w1p = (short*)(Gbuf + 8388608);                // 16384 bf16
    short* w0fp = w1p + 16384;                            // 12288 bf16
    short* wfp = w0fp + 12288;                            // 82944 bf16

    k_pack2<<<112, 256, 0, stream>>>(mw0, mw1, w1p, w0fp);
    k_packf<<<324, 256, 0, stream>>>(wf, wfp);
    k_branch<128><<<2048, 256, 0, stream>>>(feats4, w4, s4, b4, a4buf, 16384);
    k_branch<256><<<32, 256, 0, stream>>>(feats32, w32, s32, b32, a32buf, 256);
    k_cat<<<8192, 256, 0, stream>>>(feats2, w2, s2, b2, a4buf, a32buf, catb16);
    k_fuseG<<<1024, 256, 0, stream>>>(catb16, wfp, sf, bf, w0fp, Gbuf);
    k_mlp5<<<8192, 256, 0, stream>>>(Gbuf, mw0, mb0, w1p, mb1, mw2, mb2,
                                     (float*)d_out);
}